// Round 17
// baseline (136.085 us; speedup 1.0000x reference)
//
#include <hip/hip_runtime.h>

#define B_ 128
#define A_ 64
#define D_ 256
#define K_ 2048
#define R_ (B_*A_)   // 8192
#define KEFF 512
#define QB 32        // rows per fused block -> 256 blocks

typedef __attribute__((ext_vector_type(8))) short bf16x8;
typedef __attribute__((ext_vector_type(4))) float f32x4;

// ---------------- utility ----------------
__device__ inline float waveReduceSum(float v) {   // butterfly
    #pragma unroll
    for (int off = 32; off > 0; off >>= 1)
        v += __shfl_xor(v, off, 64);
    return v;
}
__device__ inline double waveReduceSumD(double v) {
    #pragma unroll
    for (int off = 32; off > 0; off >>= 1)
        v += __shfl_xor(v, off, 64);
    return v;
}
__device__ inline unsigned short f2bf(float f) {   // RNE
    unsigned int u = __float_as_uint(f);
    return (unsigned short)((u + 0x7fffu + ((u >> 16) & 1u)) >> 16);
}
__device__ inline float bf2f(unsigned short h) {
    return __uint_as_float((unsigned int)h << 16);
}
__device__ inline bool ltidx(float a, int ia, float b, int ib) {
    return a < b || (a == b && ia < ib);
}

// ---------------- PROLOGUE: convertC | col_sum_sq | useless ----------------
__global__ __launch_bounds__(256) void prologue_kernel(
        const float* __restrict__ X, const float* __restrict__ C,
        const float* __restrict__ W, const int* __restrict__ ridx,
        short* __restrict__ CP1s, float* __restrict__ csq,
        float* __restrict__ cspart, double* __restrict__ acc) {
    int bid = blockIdx.x;
    int wave = threadIdx.x >> 6, lane = threadIdx.x & 63;
    if (bid < 512) {
        // ---- convertC: CP1s [cb(16)][t(16)][kc(4)][r(128)][j(8)] ----
        int row = bid * 4 + wave;
        int korig = lane * 4;
        float4 v = *reinterpret_cast<const float4*>(C + (size_t)row * D_ + korig);
        float f[4] = {v.x, v.y, v.z, v.w};
        ushort4 hi, lo;
        unsigned short* hp = (unsigned short*)&hi;
        unsigned short* lp = (unsigned short*)&lo;
        float s = 0.f;
        #pragma unroll
        for (int q = 0; q < 4; ++q) {
            s += f[q] * f[q];
            unsigned short h = f2bf(f[q]);
            hp[q] = h;
            lp[q] = f2bf(f[q] - bf2f(h));
        }
        int rb = row >> 7, r = row & 127;
        int t = korig >> 5, kc = (korig >> 3) & 3, j = korig & 7;
        size_t base = ((size_t)rb * 16) * 4096 + (size_t)kc * 1024 + (size_t)r * 8 + j;
        *reinterpret_cast<ushort4*>(CP1s + base + (size_t)t * 4096)       = hi;
        *reinterpret_cast<ushort4*>(CP1s + base + (size_t)(t + 8) * 4096) = lo;
        s = waveReduceSum(s);
        if (lane == 0) csq[row] = s;
    } else if (bid < 576) {
        // ---- col_sum_sq partials (deep unroll -> 16 loads in flight) ----
        int idx = (bid - 512) * 256 + threadIdx.x;
        float s = 0.f;
        #pragma unroll 16
        for (int i = 0; i < B_; ++i) s += X[(size_t)i * (A_*D_) + idx];
        float p = s * s;
        p = waveReduceSum(p);
        __shared__ float red[4];
        if (lane == 0) red[wave] = p;
        __syncthreads();
        if (threadIdx.x == 0) cspart[bid - 512] = red[0] + red[1] + red[2] + red[3];
    } else {
        // ---- useless: local double W-sum (fixed reduction order), then log term ----
        double s = 0.0;
        for (int i = threadIdx.x; i < K_; i += 256) s += (double)W[i];
        __shared__ double red[256];
        red[threadIdx.x] = s; __syncthreads();
        for (int off = 128; off > 0; off >>= 1) {
            if (threadIdx.x < off) red[threadIdx.x] += red[threadIdx.x + off];
            __syncthreads();
        }
        float cutoff = (float)(red[0] / (100.0 * (double)K_));
        int k = (bid - 576) * 4 + wave;
        if (!(W[k] < cutoff)) return;
        int r = ridx[k];
        float4 xv = *reinterpret_cast<const float4*>(X + (size_t)r * D_ + lane * 4);
        float4 cv = *reinterpret_cast<const float4*>(C + (size_t)k * D_ + lane * 4);
        float u = logf(fabsf(xv.x - cv.x) + 1.f) + logf(fabsf(xv.y - cv.y) + 1.f)
                + logf(fabsf(xv.z - cv.z) + 1.f) + logf(fabsf(xv.w - cv.w) + 1.f);
        u = waveReduceSum(u);
        if (lane == 0) atomicAdd(acc + 3, (double)u);
    }
}

// ---------------- FUSED: X convert + dist MFMA + softmax + top2 + quantize + last-block finalize ----------------
// R15-proven structure (batched bfr[16] + setprio). Last finishing block
// reduces the scalars (deterministic: fixed-order fp64 over completed arrays).
__global__ __launch_bounds__(512, 2) void fused_dist_softmax(
        const short* __restrict__ CP1s, const float* __restrict__ csq,
        const float* __restrict__ X, const float* __restrict__ C,
        float* __restrict__ xsq, float* __restrict__ soft,
        float* __restrict__ outq, float* __restrict__ probs,
        float* __restrict__ qlrow, const float* __restrict__ cspart,
        double* __restrict__ acc, float* __restrict__ out_sc) {
    __shared__ short ALDS[16384];          // 32KB [seg(64)=t*4+kc][r32(32)][j(8)]
    __shared__ float csl[K_];              // 8KB
    __shared__ float xls[QB];
    __shared__ float4 wtop[8][QB];
    __shared__ float wsuml[8][QB];
    __shared__ float4 ffin[QB];
    __shared__ float finv[QB];
    __shared__ int fdone;

    int tid = threadIdx.x;
    int lane = tid & 63, w = tid >> 6;
    int S = blockIdx.x;
    int kc = lane >> 4, lr = lane & 15;

    // ---- stage csq ----
    *reinterpret_cast<float4*>(&csl[tid * 4]) =
        *reinterpret_cast<const float4*>(csq + tid * 4);

    // ---- in-kernel X convert ----
    {
        int r32 = tid >> 4;
        int c0 = (tid & 15) * 16;
        const float* xrow = X + ((size_t)S * QB + r32) * D_ + c0;
        float ssq = 0.f;
        #pragma unroll
        for (int i = 0; i < 4; ++i) {
            float4 v = *reinterpret_cast<const float4*>(xrow + 4 * i);
            float f[4] = {v.x, v.y, v.z, v.w};
            ushort4 hi, lo;
            unsigned short* hp = (unsigned short*)&hi;
            unsigned short* lp = (unsigned short*)&lo;
            #pragma unroll
            for (int q = 0; q < 4; ++q) {
                ssq += f[q] * f[q];
                unsigned short h = f2bf(f[q]);
                hp[q] = h;
                lp[q] = f2bf(f[q] - bf2f(h));
            }
            int korig = c0 + 4 * i;
            int tt = korig >> 5, kcc = (korig >> 3) & 3, j = korig & 7;
            *reinterpret_cast<ushort4*>(&ALDS[(((tt    ) * 4 + kcc) * 32 + r32) * 8 + j]) = hi;
            *reinterpret_cast<ushort4*>(&ALDS[(((tt + 8) * 4 + kcc) * 32 + r32) * 8 + j]) = lo;
        }
        #pragma unroll
        for (int off = 1; off <= 8; off <<= 1) ssq += __shfl_xor(ssq, off, 64);
        if ((lane & 15) == 0) {
            xls[r32] = ssq;
            xsq[(size_t)S * QB + r32] = ssq;
        }
    }
    __syncthreads();

    f32x4 acm[2][16] = {};

    // ---- K loop (R15 form): ta 0..8, A hi/lo once; per tau bfr[16]; setprio ----
    for (int ta = 0; ta < 8; ++ta) {
        bf16x8 a1[2], a2[2];
        #pragma unroll
        for (int rt = 0; rt < 2; ++rt) {
            a1[rt] = *(const bf16x8*)(&ALDS[((ta * 4 + kc) * 32 + rt * 16 + lr) * 8]);
            a2[rt] = *(const bf16x8*)(&ALDS[(((ta + 8) * 4 + kc) * 32 + rt * 16 + lr) * 8]);
        }
        #pragma unroll
        for (int tt = 0; tt < 2; ++tt) {
            const int tau = ta + tt * 8;
            bf16x8 bfr[16];
            #pragma unroll
            for (int g = 0; g < 4; ++g) {
                const int cb = w * 2 + (g >> 1);
                const short* bbase = CP1s + ((size_t)(cb * 16 + tau)) * 4096
                                   + (size_t)kc * 1024 + (size_t)lr * 8
                                   + (size_t)((g & 1) * 4) * 128;
                #pragma unroll
                for (int c4 = 0; c4 < 4; ++c4)
                    bfr[g * 4 + c4] = *(const bf16x8*)(bbase + c4 * 128);
            }
            __builtin_amdgcn_s_setprio(1);
            #pragma unroll
            for (int ct = 0; ct < 16; ++ct) {
                acm[0][ct] = __builtin_amdgcn_mfma_f32_16x16x32_bf16(bfr[ct], a1[0], acm[0][ct], 0, 0, 0);
                acm[0][ct] = __builtin_amdgcn_mfma_f32_16x16x32_bf16(bfr[ct], a2[0], acm[0][ct], 0, 0, 0);
                acm[1][ct] = __builtin_amdgcn_mfma_f32_16x16x32_bf16(bfr[ct], a1[1], acm[1][ct], 0, 0, 0);
                acm[1][ct] = __builtin_amdgcn_mfma_f32_16x16x32_bf16(bfr[ct], a2[1], acm[1][ct], 0, 0, 0);
            }
            __builtin_amdgcn_s_setprio(0);
        }
    }

    // Swapped C/D layout: x-row = rt*16 + (lane&15); col = w*256 + ct*16 + kc*4 + reg
    const float4* csl4 = reinterpret_cast<const float4*>(csl);

    // ---- per-row top-2; store distances back into acm for the exp pass ----
    #pragma unroll
    for (int rt = 0; rt < 2; ++rt) {
        int row32 = rt * 16 + lr;
        float xs = xls[row32];
        float bv1 = 3.4e38f, bv2 = 3.4e38f;
        int bi1 = 0x7fffffff, bi2 = 0x7fffffff;
        #pragma unroll
        for (int ct = 0; ct < 16; ++ct) {
            int col0 = w * 256 + ct * 16 + kc * 4;
            float4 cs = csl4[col0 >> 2];
            float csa[4] = {cs.x, cs.y, cs.z, cs.w};
            #pragma unroll
            for (int j = 0; j < 4; ++j) {
                float d = fmaf(-2.f, acm[rt][ct][j], xs + csa[j]);
                acm[rt][ct][j] = d;
                int idx = col0 + j;
                if (d < bv1) { bv2 = bv1; bi2 = bi1; bv1 = d; bi1 = idx; }
                else if (ltidx(d, idx, bv2, bi2)) { bv2 = d; bi2 = idx; }
            }
        }
        #pragma unroll
        for (int off = 16; off <= 32; off <<= 1) {
            float o1 = __shfl_xor(bv1, off, 64); int oi1 = __shfl_xor(bi1, off, 64);
            float o2 = __shfl_xor(bv2, off, 64); int oi2 = __shfl_xor(bi2, off, 64);
            if (ltidx(o1, oi1, bv1, bi1)) {
                if (ltidx(bv1, bi1, o2, oi2)) { bv2 = bv1; bi2 = bi1; }
                else                          { bv2 = o2;  bi2 = oi2; }
                bv1 = o1; bi1 = oi1;
            } else if (ltidx(o1, oi1, bv2, bi2)) { bv2 = o1; bi2 = oi1; }
        }
        if (kc == 0)
            wtop[w][row32] = make_float4(bv1, __int_as_float(bi1),
                                         bv2, __int_as_float(bi2));
    }
    __syncthreads();

    // ---- merge top-2 across 8 waves (threads 0..31) ----
    if (tid < QB) {
        float4 m = wtop[0][tid];
        float f1 = m.x; int a1i = __float_as_int(m.y);
        float f2 = m.z; int a2i = __float_as_int(m.w);
        #pragma unroll
        for (int ww = 1; ww < 8; ++ww) {
            float4 q = wtop[ww][tid];
            float o1 = q.x; int oi1 = __float_as_int(q.y);
            float o2 = q.z; int oi2 = __float_as_int(q.w);
            if (ltidx(o1, oi1, f1, a1i)) {
                if (ltidx(f1, a1i, o2, oi2)) { f2 = f1; a2i = a1i; }
                else                         { f2 = o2; a2i = oi2; }
                f1 = o1; a1i = oi1;
            } else if (ltidx(o1, oi1, f2, a2i)) { f2 = o1; a2i = oi1; }
        }
        ffin[tid] = make_float4(f1, __int_as_float(a1i), f2, __int_as_float(a2i));
    }
    __syncthreads();

    // ---- exp (in place over stored d) + per-row sums ----
    #pragma unroll
    for (int rt = 0; rt < 2; ++rt) {
        int row32 = rt * 16 + lr;
        float dm = ffin[row32].x;
        float psum = 0.f;
        #pragma unroll
        for (int ct = 0; ct < 16; ++ct) {
            #pragma unroll
            for (int j = 0; j < 4; ++j) {
                float e = __expf(-100.f * (acm[rt][ct][j] - dm));
                acm[rt][ct][j] = e;
                psum += e;
            }
        }
        #pragma unroll
        for (int off = 16; off <= 32; off <<= 1) psum += __shfl_xor(psum, off, 64);
        if (kc == 0) wsuml[w][row32] = psum;
    }
    __syncthreads();
    if (tid < QB) {
        float s = 0.f;
        #pragma unroll
        for (int ww = 0; ww < 8; ++ww) s += wsuml[ww][tid];
        finv[tid] = 1.f / s;
    }
    __syncthreads();

    // ---- write soft_one_hot: f32x4 stores ----
    size_t rowbase = (size_t)S * QB;
    #pragma unroll
    for (int rt = 0; rt < 2; ++rt) {
        int row32 = rt * 16 + lr;
        float inv = finv[row32];
        float* dst0 = soft + (rowbase + row32) * K_ + w * 256 + kc * 4;
        #pragma unroll
        for (int ct = 0; ct < 16; ++ct) {
            f32x4 o = acm[rt][ct] * inv;
            *reinterpret_cast<f32x4*>(dst0 + ct * 16) = o;
        }
    }

    // ---- quantize: wave w handles rows w*4 .. w*4+3; exact fp32 refine ----
    #pragma unroll
    for (int i = 0; i < 4; ++i) {
        int row32 = w * 4 + i;
        size_t grow = rowbase + row32;
        float4 fm = ffin[row32];
        int am = __float_as_int(fm.y), am2 = __float_as_int(fm.w);
        float4 x  = *reinterpret_cast<const float4*>(X + grow * D_ + lane * 4);
        float4 c1 = *reinterpret_cast<const float4*>(C + (size_t)am  * D_ + lane * 4);
        float4 c2 = *reinterpret_cast<const float4*>(C + (size_t)am2 * D_ + lane * 4);
        float d1 = (x.x-c1.x)*(x.x-c1.x) + (x.y-c1.y)*(x.y-c1.y)
                 + (x.z-c1.z)*(x.z-c1.z) + (x.w-c1.w)*(x.w-c1.w);
        float d2 = (x.x-c2.x)*(x.x-c2.x) + (x.y-c2.y)*(x.y-c2.y)
                 + (x.z-c2.z)*(x.z-c2.z) + (x.w-c2.w)*(x.w-c2.w);
        d1 = waveReduceSum(d1);
        d2 = waveReduceSum(d2);
        bool p2 = ltidx(d2, am2, d1, am);
        float4 q = p2 ? c2 : c1;
        *reinterpret_cast<float4*>(outq + grow * D_ + lane * 4) = q;
        if (lane == 0) {
            qlrow[grow] = p2 ? d2 : d1;
            probs[grow] = 1.0f / (float)K_;
        }
    }

    // ---- last-block finalize (deterministic fixed-order reduce) ----
    __threadfence();
    if (tid == 0) {
        unsigned int old = atomicAdd((unsigned int*)(acc + 6), 1u);
        fdone = (old == (unsigned int)(gridDim.x - 1)) ? 1 : 0;
    }
    __syncthreads();
    if (fdone) {
        __threadfence();   // acquire: see all blocks' writes
        double xsd = 0.0, qld = 0.0, csd = 0.0;
        for (int i = tid; i < R_; i += 512) { xsd += (double)xsq[i]; qld += (double)qlrow[i]; }
        if (tid < 64) csd = (double)cspart[tid];
        xsd = waveReduceSumD(xsd);
        qld = waveReduceSumD(qld);
        csd = waveReduceSumD(csd);
        __shared__ double ra[8], rb2[8], rc[8];
        if (lane == 0) { ra[w] = xsd; rb2[w] = qld; rc[w] = csd; }
        __syncthreads();
        if (tid == 0) {
            double xs = 0.0, ql = 0.0, cs = 0.0;
            #pragma unroll
            for (int i = 0; i < 8; ++i) { xs += ra[i]; ql += rb2[i]; cs += rc[i]; }
            out_sc[0] = (float)(ql / (double)R_);
            out_sc[1] = (float)(acc[3] / (double)K_);
            out_sc[2] = (float)(2.0 * xs / (double)R_
                             - 2.0 * cs / ((double)B_ * (double)B_ * (double)A_));
        }
    }
}

// ---------------- fallback kernels (small-ws path, proven R2 shapes) ----------------
__global__ void row_sqnorm(const float* __restrict__ X, float* __restrict__ out, int rows) {
    int wave = threadIdx.x >> 6, lane = threadIdx.x & 63;
    int row  = blockIdx.x * 4 + wave;
    if (row >= rows) return;
    float4 v = *reinterpret_cast<const float4*>(X + (size_t)row * D_ + lane * 4);
    float s = v.x*v.x + v.y*v.y + v.z*v.z + v.w*v.w;
    s = waveReduceSum(s);
    if (lane == 0) out[row] = s;
}

__global__ void col_sum_sq(const float* __restrict__ X, float* __restrict__ part) {
    int idx = blockIdx.x * blockDim.x + threadIdx.x;
    float s = 0.f;
    #pragma unroll 16
    for (int i = 0; i < B_; ++i) s += X[(size_t)i * (A_*D_) + idx];
    float p = s * s;
    p = waveReduceSum(p);
    __shared__ float red[4];
    int wave = threadIdx.x >> 6, lane = threadIdx.x & 63;
    if (lane == 0) red[wave] = p;
    __syncthreads();
    if (threadIdx.x == 0) part[blockIdx.x] = red[0] + red[1] + red[2] + red[3];
}

__global__ void wsum_kernel(const float* __restrict__ w, double* __restrict__ acc) {
    double s = 0.0;
    for (int i = threadIdx.x; i < K_; i += 256) s += (double)w[i];
    __shared__ double red[256];
    red[threadIdx.x] = s; __syncthreads();
    for (int off = 128; off > 0; off >>= 1) {
        if (threadIdx.x < off) red[threadIdx.x] += red[threadIdx.x + off];
        __syncthreads();
    }
    if (threadIdx.x == 0) acc[2] = red[0];
}

__global__ void useless_kernel(const float* __restrict__ X, const float* __restrict__ C,
                               const float* __restrict__ w, const int* __restrict__ ridx,
                               const double* __restrict__ acc_in, double* __restrict__ use_acc) {
    int wave = threadIdx.x >> 6, lane = threadIdx.x & 63;
    int k = blockIdx.x * 4 + wave;
    if (k >= K_) return;
    float cutoff = (float)(acc_in[2] / (100.0 * (double)K_));
    if (!(w[k] < cutoff)) return;
    int r = ridx[k];
    float4 xv = *reinterpret_cast<const float4*>(X + (size_t)r * D_ + lane * 4);
    float4 cv = *reinterpret_cast<const float4*>(C + (size_t)k * D_ + lane * 4);
    float s = logf(fabsf(xv.x - cv.x) + 1.f) + logf(fabsf(xv.y - cv.y) + 1.f)
            + logf(fabsf(xv.z - cv.z) + 1.f) + logf(fabsf(xv.w - cv.w) + 1.f);
    s = waveReduceSum(s);
    if (lane == 0) atomicAdd(use_acc, (double)s);
}

#define BM 128
#define BN 128
#define BK 16
__global__ __launch_bounds__(256, 4) void dist_gemm(
        const float* __restrict__ X, const float* __restrict__ C,
        const float* __restrict__ xsq, const float* __restrict__ csq,
        float* __restrict__ Dist) {
    __shared__ float As[BK][BM + 4];
    __shared__ float Bs[BK][BN + 4];
    int tid = threadIdx.x;
    int tx = tid & 15, ty = tid >> 4;
    int bm0 = blockIdx.y * BM, bn0 = blockIdx.x * BN;
    int r = tid & 127;
    const float* src = (tid < 128) ? (X + (size_t)(bm0 + r) * D_)
                                   : (C + (size_t)(bn0 + r) * D_);
    float* dst = (tid < 128) ? &As[0][0] : &Bs[0][0];
    float acc[2][2][4][4] = {};
    float4 p0 = *reinterpret_cast<const float4*>(src + 0);
    float4 p1 = *reinterpret_cast<const float4*>(src + 4);
    float4 p2 = *reinterpret_cast<const float4*>(src + 8);
    float4 p3 = *reinterpret_cast<const float4*>(src + 12);
    for (int t = 0; t < D_ / BK; ++t) {
        __syncthreads();
        dst[ 0*(BM+4) + r] = p0.x; dst[ 1*(BM+4) + r] = p0.y;
        dst[ 2*(BM+4) + r] = p0.z; dst[ 3*(BM+4) + r] = p0.w;
        dst[ 4*(BM+4) + r] = p1.x; dst[ 5*(BM+4) + r] = p1.y;
        dst[ 6*(BM+4) + r] = p1.z; dst[ 7*(BM+4) + r] = p1.w;
        dst[ 8*(BM+4) + r] = p2.x; dst[ 9*(BM+4) + r] = p2.y;
        dst[10*(BM+4) + r] = p2.z; dst[11*(BM+4) + r] = p2.w;
        dst[12*(BM+4) + r] = p3.x; dst[13*(BM+4) + r] = p3.y;
        dst[14*(BM+4) + r] = p3.z; dst[15*(BM+4) + r] = p3.w;
        __syncthreads();
        if (t < D_ / BK - 1) {
            const float* s2 = src + (t + 1) * BK;
            p0 = *reinterpret_cast<const float4*>(s2 + 0);
            p1 = *reinterpret_cast<const float4*>(s2 + 4);
            p2 = *reinterpret_cast<const float4*>(s2 + 8);
            p3 = *reinterpret_cast<const float4*>(s2 + 12);
        }
        #pragma unroll
        for (int kk = 0; kk < BK; ++kk) {
            float4 a0 = *reinterpret_cast<const float4*>(&As[kk][ty * 4]);
            float4 a1 = *reinterpret_cast<const float4*>(&As[kk][64 + ty * 4]);
            float4 b0 = *reinterpret_cast<const float4*>(&Bs[kk][tx * 4]);
            float4 b1 = *reinterpret_cast<const float4*>(&Bs[kk][64 + tx * 4]);
            float af[2][4] = {{a0.x, a0.y, a0.z, a0.w}, {a1.x, a1.y, a1.z, a1.w}};
            float bf[2][4] = {{b0.x, b0.y, b0.z, b0.w}, {b1.x, b1.y, b1.z, b1.w}};
            #pragma unroll
            for (int rg = 0; rg < 2; ++rg)
                #pragma unroll
                for (int cg = 0; cg < 2; ++cg)
                    #pragma unroll
                    for (int i = 0; i < 4; ++i)
                        #pragma unroll
                        for (int j = 0; j < 4; ++j)
                            acc[rg][cg][i][j] += af[rg][i] * bf[cg][j];
        }
    }
    #pragma unroll
    for (int rg = 0; rg < 2; ++rg)
        #pragma unroll
        for (int i = 0; i < 4; ++i) {
            int row = bm0 + rg * 64 + ty * 4 + i;
            float xs = xsq[row];
            #pragma unroll
            for (int cg = 0; cg < 2; ++cg) {
                int col = bn0 + cg * 64 + tx * 4;
                float4 cs = *reinterpret_cast<const float4*>(csq + col);
                float4 o;
                o.x = xs + cs.x - 2.f * acc[rg][cg][i][0];
                o.y = xs + cs.y - 2.f * acc[rg][cg][i][1];
                o.z = xs + cs.z - 2.f * acc[rg][cg][i][2];
                o.w = xs + cs.w - 2.f * acc[rg][cg][i][3];
                *reinterpret_cast<float4*>(Dist + (size_t)row * K_ + col) = o;
            }
        }
}

__global__ __launch_bounds__(256) void softmax_quant(
        float* __restrict__ Dist, const float* __restrict__ X,
        const float* __restrict__ C, float* __restrict__ outq,
        float* __restrict__ probs, float* __restrict__ qlrow) {
    int row = blockIdx.x;
    int t = threadIdx.x;
    int wave = t >> 6, lane = t & 63;
    float* drow = Dist + (size_t)row * K_;

    float v[8];
    float4 v0 = *reinterpret_cast<const float4*>(drow + t * 8);
    float4 v1v = *reinterpret_cast<const float4*>(drow + t * 8 + 4);
    v[0]=v0.x; v[1]=v0.y; v[2]=v0.z; v[3]=v0.w;
    v[4]=v1v.x; v[5]=v1v.y; v[6]=v1v.z; v[7]=v1v.w;

    float v1 = v[0]; int i1 = t * 8;
    float v2 = 3.4e38f; int i2 = 0x7fffffff;
    #pragma unroll
    for (int j = 1; j < 8; ++j) {
        int idx = t * 8 + j;
        if (v[j] < v1) { v2 = v1; i2 = i1; v1 = v[j]; i1 = idx; }
        else if (ltidx(v[j], idx, v2, i2)) { v2 = v[j]; i2 = idx; }
    }
    #pragma unroll
    for (int off = 32; off > 0; off >>= 1) {
        float w1 = __shfl_xor(v1, off, 64); int j1 = __shfl_xor(i1, off, 64);
        float w2 = __shfl_xor(v2, off, 64); int j2 = __shfl_xor(i2, off, 64);
        if (ltidx(w1, j1, v1, i1)) {
            if (ltidx(v1, i1, w2, j2)) { v2 = v1; i2 = i1; }
            else                       { v2 = w2; i2 = j2; }
            v1 = w1; i1 = j1;
        } else if (ltidx(w1, j1, v2, i2)) { v2 = w1; i2 = j1; }
    }
    __shared__ float sv1[4], sv2[4]; __shared__ int si1[4], si2[4];
    __shared__ float ws[4];
    if (lane == 0) { sv1[wave] = v1; si1[wave] = i1; sv2[wave] = v2; si2[wave] = i2; }
    __syncthreads();
    float dmin = sv1[0]; int am = si1[0];
    float d2nd = sv2[0]; int am2 = si2[0];
    #pragma unroll
    for (int w = 1; w < 4; ++w) {
        float w1 = sv1[w]; int j1 = si1[w];
        float w2 = sv2[w]; int j2 = si2[w];
        if (ltidx(w1, j1, dmin, am)) {
            if (ltidx(dmin, am, w2, j2)) { d2nd = dmin; am2 = am; }
            else                         { d2nd = w2;   am2 = j2; }
            dmin = w1; am = j1;
        } else if (ltidx(w1, j1, d2nd, am2)) { d2nd = w1; am2 = j1; }
    }

    float e[8]; float s = 0.f;
    #pragma unroll
    for (int j = 0; j < 8; ++j) { e[j] = __expf(-100.f * (v[j] - dmin)); s += e[j]; }
    s = waveReduceSum(s);
    if (lane == 0) ws[wave] = s;
    __syncthreads();
    float inv = 1.f / (ws[0] + ws[1] + ws[2] + ws[3]);

    float4 o0 = make_float4(e[0]*inv, e[1]*inv, e[2]*inv, e[3]*inv);
    float4 o1 = make_float4(e[4]*inv, e[5]*inv, e[6]*inv, e[7]*inv);
    *reinterpret_cast<float4*>(drow + t * 8)     = o0;
    *reinterpret_cast<float4*>(drow + t * 8 + 4) = o1;

    if (wave == 0) {
        float4 x  = *reinterpret_cast<const float4*>(X + (size_t)row * D_ + lane * 4);
        float4 c1 = *reinterpret_cast<const float4*>(C + (size_t)am  * D_ + lane * 4);
        float4 c2 = *reinterpret_cast<const float4*>(C + (size_t)am2 * D_ + lane * 4);
        float d1x = (x.x-c1.x)*(x.x-c1.x) + (x.y-c1.y)*(x.y-c1.y)
                  + (x.z-c1.z)*(x.z-c1.z) + (x.w-c1.w)*(x.w-c1.w);
        float d2x = (x.x-c2.x)*(x.x-c2.x) + (x.y-c2.y)*(x.y-c2.y)
                  + (x.z-c2.z)*(x.z-c2.z) + (x.w-c2.w)*(x.w-c2.w);
        d1x = waveReduceSum(d1x);
        d2x = waveReduceSum(d2x);
        bool pick2 = ltidx(d2x, am2, d1x, am);
        float4 q = pick2 ? c2 : c1;
        float dq = pick2 ? d2x : d1x;
        *reinterpret_cast<float4*>(outq + (size_t)row * D_ + lane * 4) = q;
        if (lane == 0) {
            qlrow[row] = dq;
            probs[row] = 1.0f / (float)K_;
        }
    }
}

// ---------------- finalize (fallback path only) ----------------
__global__ __launch_bounds__(256) void finalize_kernel(
        const double* __restrict__ acc, const float* __restrict__ xsq,
        const float* __restrict__ qlrow, const float* __restrict__ cspart,
        float* __restrict__ o) {
    int t = threadIdx.x;
    double xs = 0.0, ql = 0.0, cs = 0.0;
    for (int i = t; i < R_; i += 256) { xs += (double)xsq[i]; ql += (double)qlrow[i]; }
    if (t < 64) cs = (double)cspart[t];
    __shared__ double r0[256], r1[256], r2[256];
    r0[t] = xs; r1[t] = ql; r2[t] = cs;
    __syncthreads();
    for (int off = 128; off > 0; off >>= 1) {
        if (t < off) { r0[t] += r0[t+off]; r1[t] += r1[t+off]; r2[t] += r2[t+off]; }
        __syncthreads();
    }
    if (t == 0) {
        o[0] = (float)(r1[0] / (double)R_);
        o[1] = (float)(acc[3] / (double)K_);
        o[2] = (float)(2.0 * r0[0] / (double)R_
                     - 2.0 * r2[0] / ((double)B_ * (double)B_ * (double)A_));
    }
}

extern "C" void kernel_launch(void* const* d_in, const int* in_sizes, int n_in,
                              void* d_out, int out_size, void* d_ws, size_t ws_size,
                              hipStream_t stream) {
    const float* X  = (const float*)d_in[0];
    const float* C  = (const float*)d_in[1];
    const float* W  = (const float*)d_in[2];
    const int*   RI = (const int*)d_in[3];

    float* out    = (float*)d_out;
    float* out_q  = out;
    float* out_p  = out_q + (size_t)R_ * D_;
    float* out_s  = out_p + R_;
    float* out_sc = out_s + (size_t)R_ * K_;

    char* wsb = (char*)d_ws;
    double* acc   = (double*)wsb;                               // 8 doubles (incl. counter @ acc+6)
    float*  xsq   = (float*)(wsb + 64);                         // R_
    float*  csq   = (float*)(wsb + 64 + R_*4);                  // K_
    float*  qlrow = (float*)(wsb + 64 + R_*4 + K_*4);           // R_
    float*  cspart= (float*)(wsb + 64 + R_*4 + K_*4 + R_*4);    // 64
    short*  CP1s  = (short*)(wsb + 64 + R_*4 + K_*4 + R_*4 + 256); // 2 MB

    const size_t WS_NEEDED = 64 + (size_t)R_*4 + (size_t)K_*4 + (size_t)R_*4 + 256
                           + (size_t)K_*KEFF*2;

    hipMemsetAsync(d_ws, 0, 64, stream);   // zeroes acc[0..7] incl. completion counter

    if (ws_size >= WS_NEEDED) {
        hipLaunchKernelGGL(prologue_kernel, dim3(1088), dim3(256), 0, stream,
                           X, C, W, RI, CP1s, csq, cspart, acc);
        hipLaunchKernelGGL(fused_dist_softmax, dim3(R_/QB), dim3(512), 0, stream,
                           CP1s, csq, X, C, xsq, out_s, out_q, out_p, qlrow,
                           cspart, acc, out_sc);
    } else {
        hipLaunchKernelGGL(row_sqnorm, dim3(R_/4), dim3(256), 0, stream, X, xsq, R_);
        hipLaunchKernelGGL(row_sqnorm, dim3(K_/4), dim3(256), 0, stream, C, csq, K_);
        hipLaunchKernelGGL(col_sum_sq, dim3((A_*D_)/256), dim3(256), 0, stream, X, cspart);
        hipLaunchKernelGGL(wsum_kernel, dim3(1), dim3(256), 0, stream, W, acc);
        hipLaunchKernelGGL(useless_kernel, dim3(K_/4), dim3(256), 0, stream,
                           X, C, W, RI, acc, acc + 3);
        hipLaunchKernelGGL(dist_gemm, dim3(K_/BN, R_/BM), dim3(256), 0, stream, X, C, xsq, csq, out_s);
        hipLaunchKernelGGL(softmax_quant, dim3(R_), dim3(256), 0, stream, out_s, X, C, out_q, out_p, qlrow);
        hipLaunchKernelGGL(finalize_kernel, dim3(1), dim3(256), 0, stream, acc, xsq, qlrow, cspart, out_sc);
    }
}

// Round 18
// 78.885 us; speedup vs baseline: 1.7251x; 1.7251x over previous
//
#include <hip/hip_runtime.h>

#define B_ 128
#define A_ 64
#define D_ 256
#define K_ 2048
#define R_ (B_*A_)   // 8192
#define KEFF 512
#define QB 32        // rows per fused block -> 256 blocks

typedef __attribute__((ext_vector_type(8))) short bf16x8;
typedef __attribute__((ext_vector_type(4))) float f32x4;

// ---------------- utility ----------------
__device__ inline float waveReduceSum(float v) {   // butterfly
    #pragma unroll
    for (int off = 32; off > 0; off >>= 1)
        v += __shfl_xor(v, off, 64);
    return v;
}
__device__ inline unsigned short f2bf(float f) {   // RNE
    unsigned int u = __float_as_uint(f);
    return (unsigned short)((u + 0x7fffu + ((u >> 16) & 1u)) >> 16);
}
__device__ inline float bf2f(unsigned short h) {
    return __uint_as_float((unsigned int)h << 16);
}
__device__ inline bool ltidx(float a, int ia, float b, int ib) {
    return a < b || (a == b && ia < ib);
}

// ---------------- PROLOGUE: convertC | col_sum_sq | useless ----------------
__global__ __launch_bounds__(256) void prologue_kernel(
        const float* __restrict__ X, const float* __restrict__ C,
        const float* __restrict__ W, const int* __restrict__ ridx,
        short* __restrict__ CP1s, float* __restrict__ csq,
        float* __restrict__ cspart, double* __restrict__ acc) {
    int bid = blockIdx.x;
    int wave = threadIdx.x >> 6, lane = threadIdx.x & 63;
    if (bid < 512) {
        // ---- convertC: CP1s [cb(16)][t(16)][kc(4)][r(128)][j(8)] ----
        int row = bid * 4 + wave;
        int korig = lane * 4;
        float4 v = *reinterpret_cast<const float4*>(C + (size_t)row * D_ + korig);
        float f[4] = {v.x, v.y, v.z, v.w};
        ushort4 hi, lo;
        unsigned short* hp = (unsigned short*)&hi;
        unsigned short* lp = (unsigned short*)&lo;
        float s = 0.f;
        #pragma unroll
        for (int q = 0; q < 4; ++q) {
            s += f[q] * f[q];
            unsigned short h = f2bf(f[q]);
            hp[q] = h;
            lp[q] = f2bf(f[q] - bf2f(h));
        }
        int rb = row >> 7, r = row & 127;
        int t = korig >> 5, kc = (korig >> 3) & 3, j = korig & 7;
        size_t base = ((size_t)rb * 16) * 4096 + (size_t)kc * 1024 + (size_t)r * 8 + j;
        *reinterpret_cast<ushort4*>(CP1s + base + (size_t)t * 4096)       = hi;
        *reinterpret_cast<ushort4*>(CP1s + base + (size_t)(t + 8) * 4096) = lo;
        s = waveReduceSum(s);
        if (lane == 0) csq[row] = s;
    } else if (bid < 576) {
        // ---- col_sum_sq partials (deep unroll -> 16 loads in flight) ----
        int idx = (bid - 512) * 256 + threadIdx.x;
        float s = 0.f;
        #pragma unroll 16
        for (int i = 0; i < B_; ++i) s += X[(size_t)i * (A_*D_) + idx];
        float p = s * s;
        p = waveReduceSum(p);
        __shared__ float red[4];
        if (lane == 0) red[wave] = p;
        __syncthreads();
        if (threadIdx.x == 0) cspart[bid - 512] = red[0] + red[1] + red[2] + red[3];
    } else {
        // ---- useless: local double W-sum (fixed reduction order), then log term ----
        double s = 0.0;
        for (int i = threadIdx.x; i < K_; i += 256) s += (double)W[i];
        __shared__ double red[256];
        red[threadIdx.x] = s; __syncthreads();
        for (int off = 128; off > 0; off >>= 1) {
            if (threadIdx.x < off) red[threadIdx.x] += red[threadIdx.x + off];
            __syncthreads();
        }
        float cutoff = (float)(red[0] / (100.0 * (double)K_));
        int k = (bid - 576) * 4 + wave;
        if (!(W[k] < cutoff)) return;
        int r = ridx[k];
        float4 xv = *reinterpret_cast<const float4*>(X + (size_t)r * D_ + lane * 4);
        float4 cv = *reinterpret_cast<const float4*>(C + (size_t)k * D_ + lane * 4);
        float u = logf(fabsf(xv.x - cv.x) + 1.f) + logf(fabsf(xv.y - cv.y) + 1.f)
                + logf(fabsf(xv.z - cv.z) + 1.f) + logf(fabsf(xv.w - cv.w) + 1.f);
        u = waveReduceSum(u);
        if (lane == 0) atomicAdd(acc + 3, (double)u);
    }
}

// ---------------- FUSED: X convert + dist MFMA (swapped) + softmax + top2 + quantize ----------------
// R15-proven structure: grid 256 blocks, 512 threads = 8 waves; wave w owns
// cols [w*256, w*256+256); per-tau bfr[16] batch; setprio around MFMA cluster.
__global__ __launch_bounds__(512, 2) void fused_dist_softmax(
        const short* __restrict__ CP1s, const float* __restrict__ csq,
        const float* __restrict__ X, const float* __restrict__ C,
        float* __restrict__ xsq, float* __restrict__ soft,
        float* __restrict__ outq, float* __restrict__ probs,
        float* __restrict__ qlrow) {
    __shared__ short ALDS[16384];          // 32KB [seg(64)=t*4+kc][r32(32)][j(8)]
    __shared__ float csl[K_];              // 8KB
    __shared__ float xls[QB];
    __shared__ float4 wtop[8][QB];
    __shared__ float wsuml[8][QB];
    __shared__ float4 ffin[QB];
    __shared__ float finv[QB];

    int tid = threadIdx.x;
    int lane = tid & 63, w = tid >> 6;
    int S = blockIdx.x;
    int kc = lane >> 4, lr = lane & 15;

    // ---- stage csq ----
    *reinterpret_cast<float4*>(&csl[tid * 4]) =
        *reinterpret_cast<const float4*>(csq + tid * 4);

    // ---- in-kernel X convert ----
    {
        int r32 = tid >> 4;
        int c0 = (tid & 15) * 16;
        const float* xrow = X + ((size_t)S * QB + r32) * D_ + c0;
        float ssq = 0.f;
        #pragma unroll
        for (int i = 0; i < 4; ++i) {
            float4 v = *reinterpret_cast<const float4*>(xrow + 4 * i);
            float f[4] = {v.x, v.y, v.z, v.w};
            ushort4 hi, lo;
            unsigned short* hp = (unsigned short*)&hi;
            unsigned short* lp = (unsigned short*)&lo;
            #pragma unroll
            for (int q = 0; q < 4; ++q) {
                ssq += f[q] * f[q];
                unsigned short h = f2bf(f[q]);
                hp[q] = h;
                lp[q] = f2bf(f[q] - bf2f(h));
            }
            int korig = c0 + 4 * i;
            int tt = korig >> 5, kcc = (korig >> 3) & 3, j = korig & 7;
            *reinterpret_cast<ushort4*>(&ALDS[(((tt    ) * 4 + kcc) * 32 + r32) * 8 + j]) = hi;
            *reinterpret_cast<ushort4*>(&ALDS[(((tt + 8) * 4 + kcc) * 32 + r32) * 8 + j]) = lo;
        }
        #pragma unroll
        for (int off = 1; off <= 8; off <<= 1) ssq += __shfl_xor(ssq, off, 64);
        if ((lane & 15) == 0) {
            xls[r32] = ssq;
            xsq[(size_t)S * QB + r32] = ssq;
        }
    }
    __syncthreads();

    f32x4 acm[2][16] = {};

    // ---- K loop: ta 0..8, A hi/lo once; per tau bfr[16]; setprio ----
    for (int ta = 0; ta < 8; ++ta) {
        bf16x8 a1[2], a2[2];
        #pragma unroll
        for (int rt = 0; rt < 2; ++rt) {
            a1[rt] = *(const bf16x8*)(&ALDS[((ta * 4 + kc) * 32 + rt * 16 + lr) * 8]);
            a2[rt] = *(const bf16x8*)(&ALDS[(((ta + 8) * 4 + kc) * 32 + rt * 16 + lr) * 8]);
        }
        #pragma unroll
        for (int tt = 0; tt < 2; ++tt) {
            const int tau = ta + tt * 8;
            bf16x8 bfr[16];
            #pragma unroll
            for (int g = 0; g < 4; ++g) {
                const int cb = w * 2 + (g >> 1);
                const short* bbase = CP1s + ((size_t)(cb * 16 + tau)) * 4096
                                   + (size_t)kc * 1024 + (size_t)lr * 8
                                   + (size_t)((g & 1) * 4) * 128;
                #pragma unroll
                for (int c4 = 0; c4 < 4; ++c4)
                    bfr[g * 4 + c4] = *(const bf16x8*)(bbase + c4 * 128);
            }
            __builtin_amdgcn_s_setprio(1);
            #pragma unroll
            for (int ct = 0; ct < 16; ++ct) {
                acm[0][ct] = __builtin_amdgcn_mfma_f32_16x16x32_bf16(bfr[ct], a1[0], acm[0][ct], 0, 0, 0);
                acm[0][ct] = __builtin_amdgcn_mfma_f32_16x16x32_bf16(bfr[ct], a2[0], acm[0][ct], 0, 0, 0);
                acm[1][ct] = __builtin_amdgcn_mfma_f32_16x16x32_bf16(bfr[ct], a1[1], acm[1][ct], 0, 0, 0);
                acm[1][ct] = __builtin_amdgcn_mfma_f32_16x16x32_bf16(bfr[ct], a2[1], acm[1][ct], 0, 0, 0);
            }
            __builtin_amdgcn_s_setprio(0);
        }
    }

    // Swapped C/D layout: x-row = rt*16 + (lane&15); col = w*256 + ct*16 + kc*4 + reg
    const float4* csl4 = reinterpret_cast<const float4*>(csl);

    // ---- per-row top-2; store distances back into acm for the exp pass ----
    #pragma unroll
    for (int rt = 0; rt < 2; ++rt) {
        int row32 = rt * 16 + lr;
        float xs = xls[row32];
        float bv1 = 3.4e38f, bv2 = 3.4e38f;
        int bi1 = 0x7fffffff, bi2 = 0x7fffffff;
        #pragma unroll
        for (int ct = 0; ct < 16; ++ct) {
            int col0 = w * 256 + ct * 16 + kc * 4;
            float4 cs = csl4[col0 >> 2];
            float csa[4] = {cs.x, cs.y, cs.z, cs.w};
            #pragma unroll
            for (int j = 0; j < 4; ++j) {
                float d = fmaf(-2.f, acm[rt][ct][j], xs + csa[j]);
                acm[rt][ct][j] = d;
                int idx = col0 + j;
                if (d < bv1) { bv2 = bv1; bi2 = bi1; bv1 = d; bi1 = idx; }
                else if (ltidx(d, idx, bv2, bi2)) { bv2 = d; bi2 = idx; }
            }
        }
        #pragma unroll
        for (int off = 16; off <= 32; off <<= 1) {
            float o1 = __shfl_xor(bv1, off, 64); int oi1 = __shfl_xor(bi1, off, 64);
            float o2 = __shfl_xor(bv2, off, 64); int oi2 = __shfl_xor(bi2, off, 64);
            if (ltidx(o1, oi1, bv1, bi1)) {
                if (ltidx(bv1, bi1, o2, oi2)) { bv2 = bv1; bi2 = bi1; }
                else                          { bv2 = o2;  bi2 = oi2; }
                bv1 = o1; bi1 = oi1;
            } else if (ltidx(o1, oi1, bv2, bi2)) { bv2 = o1; bi2 = oi1; }
        }
        if (kc == 0)
            wtop[w][row32] = make_float4(bv1, __int_as_float(bi1),
                                         bv2, __int_as_float(bi2));
    }
    __syncthreads();

    // ---- merge top-2 across 8 waves (threads 0..31) ----
    if (tid < QB) {
        float4 m = wtop[0][tid];
        float f1 = m.x; int a1i = __float_as_int(m.y);
        float f2 = m.z; int a2i = __float_as_int(m.w);
        #pragma unroll
        for (int ww = 1; ww < 8; ++ww) {
            float4 q = wtop[ww][tid];
            float o1 = q.x; int oi1 = __float_as_int(q.y);
            float o2 = q.z; int oi2 = __float_as_int(q.w);
            if (ltidx(o1, oi1, f1, a1i)) {
                if (ltidx(f1, a1i, o2, oi2)) { f2 = f1; a2i = a1i; }
                else                         { f2 = o2; a2i = oi2; }
                f1 = o1; a1i = oi1;
            } else if (ltidx(o1, oi1, f2, a2i)) { f2 = o1; a2i = oi1; }
        }
        ffin[tid] = make_float4(f1, __int_as_float(a1i), f2, __int_as_float(a2i));
    }
    __syncthreads();

    // ---- exp (in place over stored d) + per-row sums ----
    #pragma unroll
    for (int rt = 0; rt < 2; ++rt) {
        int row32 = rt * 16 + lr;
        float dm = ffin[row32].x;
        float psum = 0.f;
        #pragma unroll
        for (int ct = 0; ct < 16; ++ct) {
            #pragma unroll
            for (int j = 0; j < 4; ++j) {
                float e = __expf(-100.f * (acm[rt][ct][j] - dm));
                acm[rt][ct][j] = e;
                psum += e;
            }
        }
        #pragma unroll
        for (int off = 16; off <= 32; off <<= 1) psum += __shfl_xor(psum, off, 64);
        if (kc == 0) wsuml[w][row32] = psum;
    }
    __syncthreads();
    if (tid < QB) {
        float s = 0.f;
        #pragma unroll
        for (int ww = 0; ww < 8; ++ww) s += wsuml[ww][tid];
        finv[tid] = 1.f / s;
    }
    __syncthreads();

    // ---- write soft_one_hot: f32x4 stores ----
    size_t rowbase = (size_t)S * QB;
    #pragma unroll
    for (int rt = 0; rt < 2; ++rt) {
        int row32 = rt * 16 + lr;
        float inv = finv[row32];
        float* dst0 = soft + (rowbase + row32) * K_ + w * 256 + kc * 4;
        #pragma unroll
        for (int ct = 0; ct < 16; ++ct) {
            f32x4 o = acm[rt][ct] * inv;
            *reinterpret_cast<f32x4*>(dst0 + ct * 16) = o;
        }
    }

    // ---- quantize: wave w handles rows w*4 .. w*4+3; exact fp32 refine ----
    #pragma unroll
    for (int i = 0; i < 4; ++i) {
        int row32 = w * 4 + i;
        size_t grow = rowbase + row32;
        float4 fm = ffin[row32];
        int am = __float_as_int(fm.y), am2 = __float_as_int(fm.w);
        float4 x  = *reinterpret_cast<const float4*>(X + grow * D_ + lane * 4);
        float4 c1 = *reinterpret_cast<const float4*>(C + (size_t)am  * D_ + lane * 4);
        float4 c2 = *reinterpret_cast<const float4*>(C + (size_t)am2 * D_ + lane * 4);
        float d1 = (x.x-c1.x)*(x.x-c1.x) + (x.y-c1.y)*(x.y-c1.y)
                 + (x.z-c1.z)*(x.z-c1.z) + (x.w-c1.w)*(x.w-c1.w);
        float d2 = (x.x-c2.x)*(x.x-c2.x) + (x.y-c2.y)*(x.y-c2.y)
                 + (x.z-c2.z)*(x.z-c2.z) + (x.w-c2.w)*(x.w-c2.w);
        d1 = waveReduceSum(d1);
        d2 = waveReduceSum(d2);
        bool p2 = ltidx(d2, am2, d1, am);
        float4 q = p2 ? c2 : c1;
        *reinterpret_cast<float4*>(outq + grow * D_ + lane * 4) = q;
        if (lane == 0) {
            qlrow[grow] = p2 ? d2 : d1;
            probs[grow] = 1.0f / (float)K_;
        }
    }
}

// ---------------- fallback kernels (small-ws path, proven R2 shapes) ----------------
__global__ void row_sqnorm(const float* __restrict__ X, float* __restrict__ out, int rows) {
    int wave = threadIdx.x >> 6, lane = threadIdx.x & 63;
    int row  = blockIdx.x * 4 + wave;
    if (row >= rows) return;
    float4 v = *reinterpret_cast<const float4*>(X + (size_t)row * D_ + lane * 4);
    float s = v.x*v.x + v.y*v.y + v.z*v.z + v.w*v.w;
    s = waveReduceSum(s);
    if (lane == 0) out[row] = s;
}

__global__ void col_sum_sq(const float* __restrict__ X, float* __restrict__ part) {
    int idx = blockIdx.x * blockDim.x + threadIdx.x;
    float s = 0.f;
    #pragma unroll 16
    for (int i = 0; i < B_; ++i) s += X[(size_t)i * (A_*D_) + idx];
    float p = s * s;
    p = waveReduceSum(p);
    __shared__ float red[4];
    int wave = threadIdx.x >> 6, lane = threadIdx.x & 63;
    if (lane == 0) red[wave] = p;
    __syncthreads();
    if (threadIdx.x == 0) part[blockIdx.x] = red[0] + red[1] + red[2] + red[3];
}

__global__ void wsum_kernel(const float* __restrict__ w, double* __restrict__ acc) {
    double s = 0.0;
    for (int i = threadIdx.x; i < K_; i += 256) s += (double)w[i];
    __shared__ double red[256];
    red[threadIdx.x] = s; __syncthreads();
    for (int off = 128; off > 0; off >>= 1) {
        if (threadIdx.x < off) red[threadIdx.x] += red[threadIdx.x + off];
        __syncthreads();
    }
    if (threadIdx.x == 0) acc[2] = red[0];
}

__global__ void useless_kernel(const float* __restrict__ X, const float* __restrict__ C,
                               const float* __restrict__ w, const int* __restrict__ ridx,
                               const double* __restrict__ acc_in, double* __restrict__ use_acc) {
    int wave = threadIdx.x >> 6, lane = threadIdx.x & 63;
    int k = blockIdx.x * 4 + wave;
    if (k >= K_) return;
    float cutoff = (float)(acc_in[2] / (100.0 * (double)K_));
    if (!(w[k] < cutoff)) return;
    int r = ridx[k];
    float4 xv = *reinterpret_cast<const float4*>(X + (size_t)r * D_ + lane * 4);
    float4 cv = *reinterpret_cast<const float4*>(C + (size_t)k * D_ + lane * 4);
    float s = logf(fabsf(xv.x - cv.x) + 1.f) + logf(fabsf(xv.y - cv.y) + 1.f)
            + logf(fabsf(xv.z - cv.z) + 1.f) + logf(fabsf(xv.w - cv.w) + 1.f);
    s = waveReduceSum(s);
    if (lane == 0) atomicAdd(use_acc, (double)s);
}

#define BM 128
#define BN 128
#define BK 16
__global__ __launch_bounds__(256, 4) void dist_gemm(
        const float* __restrict__ X, const float* __restrict__ C,
        const float* __restrict__ xsq, const float* __restrict__ csq,
        float* __restrict__ Dist) {
    __shared__ float As[BK][BM + 4];
    __shared__ float Bs[BK][BN + 4];
    int tid = threadIdx.x;
    int tx = tid & 15, ty = tid >> 4;
    int bm0 = blockIdx.y * BM, bn0 = blockIdx.x * BN;
    int r = tid & 127;
    const float* src = (tid < 128) ? (X + (size_t)(bm0 + r) * D_)
                                   : (C + (size_t)(bn0 + r) * D_);
    float* dst = (tid < 128) ? &As[0][0] : &Bs[0][0];
    float acc[2][2][4][4] = {};
    float4 p0 = *reinterpret_cast<const float4*>(src + 0);
    float4 p1 = *reinterpret_cast<const float4*>(src + 4);
    float4 p2 = *reinterpret_cast<const float4*>(src + 8);
    float4 p3 = *reinterpret_cast<const float4*>(src + 12);
    for (int t = 0; t < D_ / BK; ++t) {
        __syncthreads();
        dst[ 0*(BM+4) + r] = p0.x; dst[ 1*(BM+4) + r] = p0.y;
        dst[ 2*(BM+4) + r] = p0.z; dst[ 3*(BM+4) + r] = p0.w;
        dst[ 4*(BM+4) + r] = p1.x; dst[ 5*(BM+4) + r] = p1.y;
        dst[ 6*(BM+4) + r] = p1.z; dst[ 7*(BM+4) + r] = p1.w;
        dst[ 8*(BM+4) + r] = p2.x; dst[ 9*(BM+4) + r] = p2.y;
        dst[10*(BM+4) + r] = p2.z; dst[11*(BM+4) + r] = p2.w;
        dst[12*(BM+4) + r] = p3.x; dst[13*(BM+4) + r] = p3.y;
        dst[14*(BM+4) + r] = p3.z; dst[15*(BM+4) + r] = p3.w;
        __syncthreads();
        if (t < D_ / BK - 1) {
            const float* s2 = src + (t + 1) * BK;
            p0 = *reinterpret_cast<const float4*>(s2 + 0);
            p1 = *reinterpret_cast<const float4*>(s2 + 4);
            p2 = *reinterpret_cast<const float4*>(s2 + 8);
            p3 = *reinterpret_cast<const float4*>(s2 + 12);
        }
        #pragma unroll
        for (int kk = 0; kk < BK; ++kk) {
            float4 a0 = *reinterpret_cast<const float4*>(&As[kk][ty * 4]);
            float4 a1 = *reinterpret_cast<const float4*>(&As[kk][64 + ty * 4]);
            float4 b0 = *reinterpret_cast<const float4*>(&Bs[kk][tx * 4]);
            float4 b1 = *reinterpret_cast<const float4*>(&Bs[kk][64 + tx * 4]);
            float af[2][4] = {{a0.x, a0.y, a0.z, a0.w}, {a1.x, a1.y, a1.z, a1.w}};
            float bf[2][4] = {{b0.x, b0.y, b0.z, b0.w}, {b1.x, b1.y, b1.z, b1.w}};
            #pragma unroll
            for (int rg = 0; rg < 2; ++rg)
                #pragma unroll
                for (int cg = 0; cg < 2; ++cg)
                    #pragma unroll
                    for (int i = 0; i < 4; ++i)
                        #pragma unroll
                        for (int j = 0; j < 4; ++j)
                            acc[rg][cg][i][j] += af[rg][i] * bf[cg][j];
        }
    }
    #pragma unroll
    for (int rg = 0; rg < 2; ++rg)
        #pragma unroll
        for (int i = 0; i < 4; ++i) {
            int row = bm0 + rg * 64 + ty * 4 + i;
            float xs = xsq[row];
            #pragma unroll
            for (int cg = 0; cg < 2; ++cg) {
                int col = bn0 + cg * 64 + tx * 4;
                float4 cs = *reinterpret_cast<const float4*>(csq + col);
                float4 o;
                o.x = xs + cs.x - 2.f * acc[rg][cg][i][0];
                o.y = xs + cs.y - 2.f * acc[rg][cg][i][1];
                o.z = xs + cs.z - 2.f * acc[rg][cg][i][2];
                o.w = xs + cs.w - 2.f * acc[rg][cg][i][3];
                *reinterpret_cast<float4*>(Dist + (size_t)row * K_ + col) = o;
            }
        }
}

__global__ __launch_bounds__(256) void softmax_quant(
        float* __restrict__ Dist, const float* __restrict__ X,
        const float* __restrict__ C, float* __restrict__ outq,
        float* __restrict__ probs, float* __restrict__ qlrow) {
    int row = blockIdx.x;
    int t = threadIdx.x;
    int wave = t >> 6, lane = t & 63;
    float* drow = Dist + (size_t)row * K_;

    float v[8];
    float4 v0 = *reinterpret_cast<const float4*>(drow + t * 8);
    float4 v1v = *reinterpret_cast<const float4*>(drow + t * 8 + 4);
    v[0]=v0.x; v[1]=v0.y; v[2]=v0.z; v[3]=v0.w;
    v[4]=v1v.x; v[5]=v1v.y; v[6]=v1v.z; v[7]=v1v.w;

    float v1 = v[0]; int i1 = t * 8;
    float v2 = 3.4e38f; int i2 = 0x7fffffff;
    #pragma unroll
    for (int j = 1; j < 8; ++j) {
        int idx = t * 8 + j;
        if (v[j] < v1) { v2 = v1; i2 = i1; v1 = v[j]; i1 = idx; }
        else if (ltidx(v[j], idx, v2, i2)) { v2 = v[j]; i2 = idx; }
    }
    #pragma unroll
    for (int off = 32; off > 0; off >>= 1) {
        float w1 = __shfl_xor(v1, off, 64); int j1 = __shfl_xor(i1, off, 64);
        float w2 = __shfl_xor(v2, off, 64); int j2 = __shfl_xor(i2, off, 64);
        if (ltidx(w1, j1, v1, i1)) {
            if (ltidx(v1, i1, w2, j2)) { v2 = v1; i2 = i1; }
            else                       { v2 = w2; i2 = j2; }
            v1 = w1; i1 = j1;
        } else if (ltidx(w1, j1, v2, i2)) { v2 = w1; i2 = j1; }
    }
    __shared__ float sv1[4], sv2[4]; __shared__ int si1[4], si2[4];
    __shared__ float ws[4];
    if (lane == 0) { sv1[wave] = v1; si1[wave] = i1; sv2[wave] = v2; si2[wave] = i2; }
    __syncthreads();
    float dmin = sv1[0]; int am = si1[0];
    float d2nd = sv2[0]; int am2 = si2[0];
    #pragma unroll
    for (int w = 1; w < 4; ++w) {
        float w1 = sv1[w]; int j1 = si1[w];
        float w2 = sv2[w]; int j2 = si2[w];
        if (ltidx(w1, j1, dmin, am)) {
            if (ltidx(dmin, am, w2, j2)) { d2nd = dmin; am2 = am; }
            else                         { d2nd = w2;   am2 = j2; }
            dmin = w1; am = j1;
        } else if (ltidx(w1, j1, d2nd, am2)) { d2nd = w1; am2 = j1; }
    }

    float e[8]; float s = 0.f;
    #pragma unroll
    for (int j = 0; j < 8; ++j) { e[j] = __expf(-100.f * (v[j] - dmin)); s += e[j]; }
    s = waveReduceSum(s);
    if (lane == 0) ws[wave] = s;
    __syncthreads();
    float inv = 1.f / (ws[0] + ws[1] + ws[2] + ws[3]);

    float4 o0 = make_float4(e[0]*inv, e[1]*inv, e[2]*inv, e[3]*inv);
    float4 o1 = make_float4(e[4]*inv, e[5]*inv, e[6]*inv, e[7]*inv);
    *reinterpret_cast<float4*>(drow + t * 8)     = o0;
    *reinterpret_cast<float4*>(drow + t * 8 + 4) = o1;

    if (wave == 0) {
        float4 x  = *reinterpret_cast<const float4*>(X + (size_t)row * D_ + lane * 4);
        float4 c1 = *reinterpret_cast<const float4*>(C + (size_t)am  * D_ + lane * 4);
        float4 c2 = *reinterpret_cast<const float4*>(C + (size_t)am2 * D_ + lane * 4);
        float d1x = (x.x-c1.x)*(x.x-c1.x) + (x.y-c1.y)*(x.y-c1.y)
                  + (x.z-c1.z)*(x.z-c1.z) + (x.w-c1.w)*(x.w-c1.w);
        float d2x = (x.x-c2.x)*(x.x-c2.x) + (x.y-c2.y)*(x.y-c2.y)
                  + (x.z-c2.z)*(x.z-c2.z) + (x.w-c2.w)*(x.w-c2.w);
        d1x = waveReduceSum(d1x);
        d2x = waveReduceSum(d2x);
        bool pick2 = ltidx(d2x, am2, d1x, am);
        float4 q = pick2 ? c2 : c1;
        float dq = pick2 ? d2x : d1x;
        *reinterpret_cast<float4*>(outq + (size_t)row * D_ + lane * 4) = q;
        if (lane == 0) {
            qlrow[row] = dq;
            probs[row] = 1.0f / (float)K_;
        }
    }
}

// ---------------- finalize ----------------
__global__ __launch_bounds__(256) void finalize_kernel(
        const double* __restrict__ acc, const float* __restrict__ xsq,
        const float* __restrict__ qlrow, const float* __restrict__ cspart,
        float* __restrict__ o) {
    int t = threadIdx.x;
    double xs = 0.0, ql = 0.0, cs = 0.0;
    for (int i = t; i < R_; i += 256) { xs += (double)xsq[i]; ql += (double)qlrow[i]; }
    if (t < 64) cs = (double)cspart[t];
    __shared__ double r0[256], r1[256], r2[256];
    r0[t] = xs; r1[t] = ql; r2[t] = cs;
    __syncthreads();
    for (int off = 128; off > 0; off >>= 1) {
        if (t < off) { r0[t] += r0[t+off]; r1[t] += r1[t+off]; r2[t] += r2[t+off]; }
        __syncthreads();
    }
    if (t == 0) {
        o[0] = (float)(r1[0] / (double)R_);
        o[1] = (float)(acc[3] / (double)K_);
        o[2] = (float)(2.0 * r0[0] / (double)R_
                     - 2.0 * r2[0] / ((double)B_ * (double)B_ * (double)A_));
    }
}

extern "C" void kernel_launch(void* const* d_in, const int* in_sizes, int n_in,
                              void* d_out, int out_size, void* d_ws, size_t ws_size,
                              hipStream_t stream) {
    const float* X  = (const float*)d_in[0];
    const float* C  = (const float*)d_in[1];
    const float* W  = (const float*)d_in[2];
    const int*   RI = (const int*)d_in[3];

    float* out    = (float*)d_out;
    float* out_q  = out;
    float* out_p  = out_q + (size_t)R_ * D_;
    float* out_s  = out_p + R_;
    float* out_sc = out_s + (size_t)R_ * K_;

    char* wsb = (char*)d_ws;
    double* acc   = (double*)wsb;                               // 8 doubles
    float*  xsq   = (float*)(wsb + 64);                         // R_
    float*  csq   = (float*)(wsb + 64 + R_*4);                  // K_
    float*  qlrow = (float*)(wsb + 64 + R_*4 + K_*4);           // R_
    float*  cspart= (float*)(wsb + 64 + R_*4 + K_*4 + R_*4);    // 64
    short*  CP1s  = (short*)(wsb + 64 + R_*4 + K_*4 + R_*4 + 256); // 2 MB

    const size_t WS_NEEDED = 64 + (size_t)R_*4 + (size_t)K_*4 + (size_t)R_*4 + 256
                           + (size_t)K_*KEFF*2;

    hipMemsetAsync(d_ws, 0, 64, stream);

    if (ws_size >= WS_NEEDED) {
        hipLaunchKernelGGL(prologue_kernel, dim3(1088), dim3(256), 0, stream,
                           X, C, W, RI, CP1s, csq, cspart, acc);
        hipLaunchKernelGGL(fused_dist_softmax, dim3(R_/QB), dim3(512), 0, stream,
                           CP1s, csq, X, C, xsq, out_s, out_q, out_p, qlrow);
    } else {
        hipLaunchKernelGGL(row_sqnorm, dim3(R_/4), dim3(256), 0, stream, X, xsq, R_);
        hipLaunchKernelGGL(row_sqnorm, dim3(K_/4), dim3(256), 0, stream, C, csq, K_);
        hipLaunchKernelGGL(col_sum_sq, dim3((A_*D_)/256), dim3(256), 0, stream, X, cspart);
        hipLaunchKernelGGL(wsum_kernel, dim3(1), dim3(256), 0, stream, W, acc);
        hipLaunchKernelGGL(useless_kernel, dim3(K_/4), dim3(256), 0, stream,
                           X, C, W, RI, acc, acc + 3);
        hipLaunchKernelGGL(dist_gemm, dim3(K_/BN, R_/BM), dim3(256), 0, stream, X, C, xsq, csq, out_s);
        hipLaunchKernelGGL(softmax_quant, dim3(R_), dim3(256), 0, stream, out_s, X, C, out_q, out_p, qlrow);
    }

    hipLaunchKernelGGL(finalize_kernel, dim3(1), dim3(256), 0, stream, acc, xsq, qlrow, cspart, out_sc);
}